// Round 3
// baseline (186.371 us; speedup 1.0000x reference)
//
#include <hip/hip_runtime.h>
#include <hip/hip_bf16.h>

constexpr int kNV = 8;
constexpr int kHF = 26;
constexpr int kWF = 88;
constexpr int kC  = 256;
constexpr int kP  = 4;
constexpr int kNU = 33;
constexpr int kNH = 64;
constexpr int kLQ = kNU * kNH;   // 2112

// ---------------- prep: WoutWp = Wout@Wp (256), constWp = bout.Wp ----------------------
__global__ void k_prep(const float* __restrict__ Wout, const float* __restrict__ bout,
                       const float* __restrict__ Wp,
                       float* __restrict__ WoutWp, float* __restrict__ constWp) {
  int tid = threadIdx.x;  // 256 threads, 1 block
  float s = 0.f;
  for (int j = 0; j < kC; ++j) s += Wout[(size_t)tid * kC + j] * Wp[j];
  WoutWp[tid] = s;

  __shared__ float red[256];
  red[tid] = bout[tid] * Wp[tid];
  __syncthreads();
  for (int off = 128; off > 0; off >>= 1) {
    if (tid < off) red[tid] += red[tid + off];
    __syncthreads();
  }
  if (tid == 0) constWp[0] = red[0];
}

// ---------------- geometry: u,v per (b,v,q) + keep_index -------------------------------
__global__ void k_geom(const float* __restrict__ camk, float* __restrict__ uv,
                       float* __restrict__ out_keep, int bs) {
  int t = blockIdx.x * 256 + threadIdx.x;
  if (t >= bs * kLQ) return;
  int b = t / kLQ;
  int ij = t - b * kLQ;
  int i = ij / kNH;
  int j = ij - i * kNH;
  const float* K = camk + b * 9;
  // grid computed in double then cast, matching np.linspace->astype(f32)
  float g0 = (float)(-25.6 + (double)j * (51.2 / 63.0));  //  y
  float g2 = (float)(25.6 - (double)i * 0.8);             // -x
  bool any = false;
  for (int k = 0; k < kNV; ++k) {
    float g1 = (float)(4.0 - (double)k * (8.0 / 7.0));    // -z
    float p0 = K[0] * g0 + K[1] * g1 + K[2] * g2;
    float p1 = K[3] * g0 + K[4] * g1 + K[5] * g2;
    float p2 = K[6] * g0 + K[7] * g1 + K[8] * g2;
    float den = (fabsf(p2) < 1e-6f) ? 1e-6f : p2;
    float u = p0 / den / 1408.0f;
    float v = p1 / den / 416.0f;
    any = any || (u >= 0.f && u <= 1.f && v >= 0.f && v <= 1.f);
    float* dst = uv + ((size_t)(b * kNV + k) * kLQ + ij) * 2;
    dst[0] = u;
    dst[1] = v;
  }
  out_keep[t] = any ? 1.f : 0.f;
}

// ---------------- simple 16x16 tiled fp32 GEMM: out = A@B + bias -----------------------
// one thread per output element; K multiple of 16.
__global__ __launch_bounds__(256) void gemm16(const float* __restrict__ A,
                                              const float* __restrict__ B,
                                              const float* __restrict__ bias,
                                              float* __restrict__ out,
                                              int M, int N, int K) {
  __shared__ float As[16][17];
  __shared__ float Bs[16][17];
  int tx = threadIdx.x & 15;
  int ty = threadIdx.x >> 4;
  int row = blockIdx.y * 16 + ty;
  int col = blockIdx.x * 16 + tx;
  float acc = 0.f;
  for (int k0 = 0; k0 < K; k0 += 16) {
    As[ty][tx] = (row < M) ? A[(size_t)row * K + k0 + tx] : 0.f;
    Bs[ty][tx] = (col < N) ? B[(size_t)(k0 + ty) * N + col] : 0.f;
    __syncthreads();
#pragma unroll
    for (int kk = 0; kk < 16; ++kk) acc += As[ty][kk] * Bs[kk][tx];
    __syncthreads();
  }
  if (row < M && col < N) out[(size_t)row * N + col] = acc + bias[col];
}

// ---------------- fused: sample + height softmax/argmax + weighted msda + @Wout --------
__global__ __launch_bounds__(256) void k_fused(
    const float* __restrict__ valp, const float* __restrict__ uv,
    const float* __restrict__ qoff, const float* __restrict__ qattn,
    const float* __restrict__ qdot, const float* __restrict__ WoutWp,
    const float* __restrict__ constWp, const float* __restrict__ Wout,
    const float* __restrict__ bout, const float* __restrict__ query,
    float* __restrict__ out_grd, float* __restrict__ out_mhi) {
  int bq = blockIdx.x;            // b*kLQ + q
  int q = bq % kLQ;
  int b = bq / kLQ;
  int tid = threadIdx.x;          // channel = h*32 + d = tid
  int h = tid >> 5;
  int lane = tid & 63;
  int wid = tid >> 6;

  // attention softmax over P for this head (same values across the 32 d-lanes)
  const float* qa = qattn + (size_t)bq * 32 + h * 4;
  float a0 = qa[0], a1 = qa[1], a2 = qa[2], a3 = qa[3];
  float am = fmaxf(fmaxf(a0, a1), fmaxf(a2, a3));
  float e0 = expf(a0 - am), e1 = expf(a1 - am), e2 = expf(a2 - am), e3 = expf(a3 - am);
  float ei = 1.f / (e0 + e1 + e2 + e3);
  float aw[4] = {e0 * ei, e1 * ei, e2 * ei, e3 * ei};

  // sampling offsets for this head: off[h][p][{x,y}]
  const float* qo = qoff + (size_t)bq * 64 + h * 8;
  float offx[4], offy[4];
#pragma unroll
  for (int p = 0; p < 4; ++p) { offx[p] = qo[p * 2]; offy[p] = qo[p * 2 + 1]; }

  const float* vp = valp + (size_t)b * (kHF * kWF) * kC + tid;

  float sv[kNV];
  __shared__ float red[kNV][4];
  __shared__ float lgs[kNV];
  __shared__ float wk[kNV];
  __shared__ float msda_s[kC];

  for (int v = 0; v < kNV; ++v) {
    size_t uvi = ((size_t)(b * kNV + v) * kLQ + q) * 2;
    float ub = uv[uvi]     * 88.0f - 0.5f;
    float vb = uv[uvi + 1] * 26.0f - 0.5f;
    float s = 0.f;
#pragma unroll
    for (int p = 0; p < kP; ++p) {
      float px = ub + offx[p];
      float py = vb + offy[p];
      px = fminf(fmaxf(px, -10000.f), 10000.f);
      py = fminf(fmaxf(py, -10000.f), 10000.f);
      float x0f = floorf(px), y0f = floorf(py);
      float lx = px - x0f, ly = py - y0f;
      int x0 = (int)x0f, y0 = (int)y0f;
      float samp = 0.f;
#pragma unroll
      for (int cy = 0; cy < 2; ++cy) {
#pragma unroll
        for (int cx = 0; cx < 2; ++cx) {
          int xi = x0 + cx, yi = y0 + cy;
          float w = (cx ? lx : 1.f - lx) * (cy ? ly : 1.f - ly);
          bool valid = (xi >= 0) && (xi < kWF) && (yi >= 0) && (yi < kHF);
          int xc = xi < 0 ? 0 : (xi > kWF - 1 ? kWF - 1 : xi);
          int yc = yi < 0 ? 0 : (yi > kHF - 1 ? kHF - 1 : yi);
          float g = vp[((size_t)yc * kWF + xc) * kC];
          samp += valid ? g * w : 0.f;
        }
      }
      s += aw[p] * samp;
    }
    sv[v] = s;
    // block-reduce s * WoutWp[tid] -> logit contribution
    float lv = s * WoutWp[tid];
#pragma unroll
    for (int o = 32; o > 0; o >>= 1) lv += __shfl_down(lv, o, 64);
    if (lane == 0) red[v][wid] = lv;   // each slot written exactly once
  }
  __syncthreads();
  if (tid < kNV)
    lgs[tid] = red[tid][0] + red[tid][1] + red[tid][2] + red[tid][3] +
               qdot[bq] + constWp[0];
  __syncthreads();
  if (tid == 0) {
    float m = -1e30f; int ai = 0;
    for (int v = 0; v < kNV; ++v)
      if (lgs[v] > m) { m = lgs[v]; ai = v; }
    float ev[kNV]; float ssum = 0.f;
    for (int v = 0; v < kNV; ++v) { ev[v] = expf(lgs[v] - m); ssum += ev[v]; }
    float invs = 1.f / ssum;
    for (int v = 0; v < kNV; ++v) wk[v] = ev[v] * invs;
    out_mhi[bq] = (float)ai;
  }
  __syncthreads();
  float acc = 0.f;
#pragma unroll
  for (int v = 0; v < kNV; ++v) acc += wk[v] * sv[v];
  msda_s[tid] = acc;
  __syncthreads();
  // matvec: out[bq][tid] = msda . Wout[:,tid] + bout[tid] + 2*query[bq][tid]
  float o = 0.f;
  const float* wcol = Wout + tid;
#pragma unroll 4
  for (int k = 0; k < kC; ++k) o += msda_s[k] * wcol[(size_t)k * kC];
  o += bout[tid] + 2.0f * query[(size_t)bq * kC + tid];
  out_grd[(size_t)bq * kC + tid] = o;
}

extern "C" void kernel_launch(void* const* d_in, const int* in_sizes, int n_in,
                              void* d_out, int out_size, void* d_ws, size_t ws_size,
                              hipStream_t stream) {
  if (n_in < 13) return;
  const float* query = (const float*)d_in[0];
  const float* value = (const float*)d_in[1];
  const float* camk  = (const float*)d_in[2];
  const float* Wv    = (const float*)d_in[3];
  const float* bv    = (const float*)d_in[4];
  const float* Wo    = (const float*)d_in[5];
  const float* bo    = (const float*)d_in[6];
  const float* Wa    = (const float*)d_in[7];
  const float* ba    = (const float*)d_in[8];
  const float* Wout  = (const float*)d_in[9];
  const float* bout  = (const float*)d_in[10];
  const float* Wp    = (const float*)d_in[11];
  const float* bp    = (const float*)d_in[12];
  int bs = in_sizes[0] / (kLQ * kC);
  int MQ = bs * kLQ;          // 4224
  int MV = bs * kHF * kWF;    // 4576

  float* ws = (float*)d_ws;
  size_t o = 0;
  float* valp    = ws + o; o += (size_t)MV * kC;       // 1,171,456
  float* uv      = ws + o; o += (size_t)bs * kNV * kLQ * 2;
  float* qoff    = ws + o; o += (size_t)MQ * 64;
  float* qattn   = ws + o; o += (size_t)MQ * 32;
  float* qdot    = ws + o; o += (size_t)MQ;
  float* WoutWp  = ws + o; o += kC;
  float* constWp = ws + o; o += 1;
  (void)ws_size; (void)out_size;

  float* outp = (float*)d_out;
  float* out_grd  = outp;                          // bs*LQ*C
  float* out_mhi  = outp + (size_t)MQ * kC;        // bs*LQ
  float* out_keep = out_mhi + (size_t)MQ;          // bs*LQ

  k_prep<<<1, 256, 0, stream>>>(Wout, bout, Wp, WoutWp, constWp);
  k_geom<<<(MQ + 255) / 256, 256, 0, stream>>>(camk, uv, out_keep, bs);
  gemm16<<<dim3(16, (MV + 15) / 16), 256, 0, stream>>>(value, Wv, bv, valp, MV, kC, kC);
  gemm16<<<dim3(4,  (MQ + 15) / 16), 256, 0, stream>>>(query, Wo, bo, qoff,  MQ, 64, kC);
  gemm16<<<dim3(2,  (MQ + 15) / 16), 256, 0, stream>>>(query, Wa, ba, qattn, MQ, 32, kC);
  gemm16<<<dim3(1,  (MQ + 15) / 16), 256, 0, stream>>>(query, Wp, bp, qdot,  MQ, 1,  kC);
  k_fused<<<MQ, 256, 0, stream>>>(valp, uv, qoff, qattn, qdot, WoutWp, constWp,
                                  Wout, bout, query, out_grd, out_mhi);
}

// Round 4
// 166.608 us; speedup vs baseline: 1.1186x; 1.1186x over previous
//
#include <hip/hip_runtime.h>
#include <hip/hip_bf16.h>

constexpr int kNV = 8;
constexpr int kHF = 26;
constexpr int kWF = 88;
constexpr int kC  = 256;
constexpr int kP  = 4;
constexpr int kNU = 33;
constexpr int kNH = 64;
constexpr int kLQ = kNU * kNH;   // 2112

// ---------------- prep: WoutWp = Wout@Wp (256), constWp = bout.Wp ----------------------
__global__ void k_prep(const float* __restrict__ Wout, const float* __restrict__ bout,
                       const float* __restrict__ Wp,
                       float* __restrict__ WoutWp, float* __restrict__ constWp) {
  int tid = threadIdx.x;  // 256 threads, 1 block
  float s = 0.f;
  for (int j = 0; j < kC; ++j) s += Wout[(size_t)tid * kC + j] * Wp[j];
  WoutWp[tid] = s;

  __shared__ float red[256];
  red[tid] = bout[tid] * Wp[tid];
  __syncthreads();
  for (int off = 128; off > 0; off >>= 1) {
    if (tid < off) red[tid] += red[tid + off];
    __syncthreads();
  }
  if (tid == 0) constWp[0] = red[0];
}

// ---------------- geometry: u,v per (b,v,q) + keep_index -------------------------------
__global__ void k_geom(const float* __restrict__ camk, float* __restrict__ uv,
                       float* __restrict__ out_keep, int bs) {
  int t = blockIdx.x * 256 + threadIdx.x;
  if (t >= bs * kLQ) return;
  int b = t / kLQ;
  int ij = t - b * kLQ;
  int i = ij / kNH;
  int j = ij - i * kNH;
  const float* K = camk + b * 9;
  float g0 = (float)(-25.6 + (double)j * (51.2 / 63.0));  //  y
  float g2 = (float)(25.6 - (double)i * 0.8);             // -x
  bool any = false;
  for (int k = 0; k < kNV; ++k) {
    float g1 = (float)(4.0 - (double)k * (8.0 / 7.0));    // -z
    float p0 = K[0] * g0 + K[1] * g1 + K[2] * g2;
    float p1 = K[3] * g0 + K[4] * g1 + K[5] * g2;
    float p2 = K[6] * g0 + K[7] * g1 + K[8] * g2;
    float den = (fabsf(p2) < 1e-6f) ? 1e-6f : p2;
    float u = p0 / den / 1408.0f;
    float v = p1 / den / 416.0f;
    any = any || (u >= 0.f && u <= 1.f && v >= 0.f && v <= 1.f);
    float* dst = uv + ((size_t)(b * kNV + k) * kLQ + ij) * 2;
    dst[0] = u;
    dst[1] = v;
  }
  out_keep[t] = any ? 1.f : 0.f;
}

// ---------------- 64x64 tiled fp32 GEMM ------------------------------------------------
// MODE 0: out = A@B + bias ; MODE 1: out = A@B + bias + 2*resid
template <int MODE>
__global__ __launch_bounds__(256) void gemm_f(
    const float* __restrict__ A, const float* __restrict__ B,
    const float* __restrict__ bias, const float* __restrict__ resid,
    float* __restrict__ out, int M, int N, int K) {
  __shared__ float As[64][17];
  __shared__ float Bs[16][64];
  int tid = threadIdx.x;
  int tx = tid & 15, ty = tid >> 4;
  int row0 = blockIdx.y * 64;
  int col0 = blockIdx.x * 64;
  float acc[4][4] = {};
  for (int k0 = 0; k0 < K; k0 += 16) {
#pragma unroll
    for (int l = 0; l < 4; ++l) {
      int e = tid + l * 256;
      int r = e >> 4, kk = e & 15;
      int gr = row0 + r;
      As[r][kk] = (gr < M) ? A[(size_t)gr * K + k0 + kk] : 0.f;
    }
#pragma unroll
    for (int l = 0; l < 4; ++l) {
      int e = tid + l * 256;
      int kk = e >> 6, c = e & 63;
      int gc = col0 + c;
      Bs[kk][c] = (gc < N) ? B[(size_t)(k0 + kk) * N + gc] : 0.f;
    }
    __syncthreads();
#pragma unroll
    for (int kk = 0; kk < 16; ++kk) {
      float av[4];
#pragma unroll
      for (int i = 0; i < 4; ++i) av[i] = As[ty * 4 + i][kk];
      float4 b4 = *reinterpret_cast<const float4*>(&Bs[kk][tx * 4]);
      float bvv[4] = {b4.x, b4.y, b4.z, b4.w};
#pragma unroll
      for (int i = 0; i < 4; ++i)
#pragma unroll
        for (int jj = 0; jj < 4; ++jj) acc[i][jj] += av[i] * bvv[jj];
    }
    __syncthreads();
  }
#pragma unroll
  for (int i = 0; i < 4; ++i) {
    int gr = row0 + ty * 4 + i;
    if (gr >= M) continue;
#pragma unroll
    for (int jj = 0; jj < 4; ++jj) {
      int gc = col0 + tx * 4 + jj;
      if (gc >= N) continue;
      float v = acc[i][jj] + bias[gc];
      if (MODE == 1) v += 2.0f * resid[(size_t)gr * N + gc];
      out[(size_t)gr * N + gc] = v;
    }
  }
}

// ---------------- simple 16x16 tiled fp32 GEMM (small N projections) -------------------
__global__ __launch_bounds__(256) void gemm16(const float* __restrict__ A,
                                              const float* __restrict__ B,
                                              const float* __restrict__ bias,
                                              float* __restrict__ out,
                                              int M, int N, int K) {
  __shared__ float As[16][17];
  __shared__ float Bs[16][17];
  int tx = threadIdx.x & 15;
  int ty = threadIdx.x >> 4;
  int row = blockIdx.y * 16 + ty;
  int col = blockIdx.x * 16 + tx;
  float acc = 0.f;
  for (int k0 = 0; k0 < K; k0 += 16) {
    As[ty][tx] = (row < M) ? A[(size_t)row * K + k0 + tx] : 0.f;
    Bs[ty][tx] = (col < N) ? B[(size_t)(k0 + ty) * N + col] : 0.f;
    __syncthreads();
#pragma unroll
    for (int kk = 0; kk < 16; ++kk) acc += As[ty][kk] * Bs[kk][tx];
    __syncthreads();
  }
  if (row < M && col < N) out[(size_t)row * N + col] = acc + bias[col];
}

// ---------------- fused sampling: one wave per (b,q) -----------------------------------
// lane l: head h = l>>3, channels h*32 + (l&7)*4 .. +3 (float4)
__global__ __launch_bounds__(256) void k_fused(
    const float* __restrict__ valp, const float* __restrict__ uv,
    const float* __restrict__ qoff, const float* __restrict__ qattn,
    const float* __restrict__ qdot, const float* __restrict__ WoutWp,
    const float* __restrict__ constWp,
    float* __restrict__ msda_w, float* __restrict__ out_mhi) {
  int wid = threadIdx.x >> 6;
  int lane = threadIdx.x & 63;
  int bq = blockIdx.x * 4 + wid;
  int q = bq % kLQ;
  int b = bq / kLQ;
  int h = lane >> 3;
  int dq = lane & 7;
  int ch = h * 32 + dq * 4;

  // attention softmax over P for this head
  const float* qa = qattn + (size_t)bq * 32 + h * 4;
  float a0 = qa[0], a1 = qa[1], a2 = qa[2], a3 = qa[3];
  float am = fmaxf(fmaxf(a0, a1), fmaxf(a2, a3));
  float e0 = expf(a0 - am), e1 = expf(a1 - am), e2 = expf(a2 - am), e3 = expf(a3 - am);
  float ei = 1.f / (e0 + e1 + e2 + e3);
  float aw[4] = {e0 * ei, e1 * ei, e2 * ei, e3 * ei};

  const float* qo = qoff + (size_t)bq * 64 + h * 8;
  float offx[4], offy[4];
#pragma unroll
  for (int p = 0; p < 4; ++p) { offx[p] = qo[p * 2]; offy[p] = qo[p * 2 + 1]; }

  const float* vp = valp + (size_t)b * (kHF * kWF) * kC + ch;
  float4 w4 = *reinterpret_cast<const float4*>(WoutWp + ch);

  float4 sv[kNV];
  float lg[kNV];

#pragma unroll
  for (int v = 0; v < kNV; ++v) {
    size_t uvi = ((size_t)(b * kNV + v) * kLQ + q) * 2;
    float ub = uv[uvi]     * 88.0f - 0.5f;
    float vb = uv[uvi + 1] * 26.0f - 0.5f;
    float4 s4 = {0.f, 0.f, 0.f, 0.f};
#pragma unroll
    for (int p = 0; p < kP; ++p) {
      float px = ub + offx[p];
      float py = vb + offy[p];
      px = fminf(fmaxf(px, -10000.f), 10000.f);
      py = fminf(fmaxf(py, -10000.f), 10000.f);
      float x0f = floorf(px), y0f = floorf(py);
      float lx = px - x0f, ly = py - y0f;
      int x0 = (int)x0f, y0 = (int)y0f;
#pragma unroll
      for (int cy = 0; cy < 2; ++cy) {
#pragma unroll
        for (int cx = 0; cx < 2; ++cx) {
          int xi = x0 + cx, yi = y0 + cy;
          float w = (cx ? lx : 1.f - lx) * (cy ? ly : 1.f - ly) * aw[p];
          bool valid = (xi >= 0) && (xi < kWF) && (yi >= 0) && (yi < kHF);
          int xc = xi < 0 ? 0 : (xi > kWF - 1 ? kWF - 1 : xi);
          int yc = yi < 0 ? 0 : (yi > kHF - 1 ? kHF - 1 : yi);
          float4 g = *reinterpret_cast<const float4*>(vp + (size_t)(yc * kWF + xc) * kC);
          float wv = valid ? w : 0.f;
          s4.x += wv * g.x; s4.y += wv * g.y; s4.z += wv * g.z; s4.w += wv * g.w;
        }
      }
    }
    sv[v] = s4;
    // wave-reduce logit contribution
    float lv = s4.x * w4.x + s4.y * w4.y + s4.z * w4.z + s4.w * w4.w;
#pragma unroll
    for (int o = 32; o > 0; o >>= 1) lv += __shfl_down(lv, o, 64);
    lg[v] = lv;  // true value in lane 0 only
  }

  // lane 0: height softmax + argmax
  float wk[kNV];
  if (lane == 0) {
    float qd = qdot[bq] + constWp[0];
    float m = -1e30f; int ai = 0;
#pragma unroll
    for (int v = 0; v < kNV; ++v) {
      lg[v] += qd;
      if (lg[v] > m) { m = lg[v]; ai = v; }
    }
    float ssum = 0.f;
#pragma unroll
    for (int v = 0; v < kNV; ++v) { wk[v] = expf(lg[v] - m); ssum += wk[v]; }
    float invs = 1.f / ssum;
#pragma unroll
    for (int v = 0; v < kNV; ++v) wk[v] *= invs;
    out_mhi[bq] = (float)ai;
  }
  float4 acc = {0.f, 0.f, 0.f, 0.f};
#pragma unroll
  for (int v = 0; v < kNV; ++v) {
    float wv = __shfl(wk[v], 0, 64);
    acc.x += wv * sv[v].x; acc.y += wv * sv[v].y;
    acc.z += wv * sv[v].z; acc.w += wv * sv[v].w;
  }
  *reinterpret_cast<float4*>(msda_w + (size_t)bq * kC + ch) = acc;
}

extern "C" void kernel_launch(void* const* d_in, const int* in_sizes, int n_in,
                              void* d_out, int out_size, void* d_ws, size_t ws_size,
                              hipStream_t stream) {
  if (n_in < 13) return;
  const float* query = (const float*)d_in[0];
  const float* value = (const float*)d_in[1];
  const float* camk  = (const float*)d_in[2];
  const float* Wv    = (const float*)d_in[3];
  const float* bv    = (const float*)d_in[4];
  const float* Wo    = (const float*)d_in[5];
  const float* bo    = (const float*)d_in[6];
  const float* Wa    = (const float*)d_in[7];
  const float* ba    = (const float*)d_in[8];
  const float* Wout  = (const float*)d_in[9];
  const float* bout  = (const float*)d_in[10];
  const float* Wp    = (const float*)d_in[11];
  const float* bp    = (const float*)d_in[12];
  int bs = in_sizes[0] / (kLQ * kC);
  int MQ = bs * kLQ;          // 4224
  int MV = bs * kHF * kWF;    // 4576

  float* ws = (float*)d_ws;
  size_t o = 0;
  float* valp    = ws + o; o += (size_t)MV * kC;
  float* uv      = ws + o; o += (size_t)bs * kNV * kLQ * 2;
  float* qoff    = ws + o; o += (size_t)MQ * 64;
  float* qattn   = ws + o; o += (size_t)MQ * 32;
  float* qdot    = ws + o; o += (size_t)MQ;
  float* msda_w  = ws + o; o += (size_t)MQ * kC;
  float* WoutWp  = ws + o; o += kC;
  float* constWp = ws + o; o += 1;
  (void)ws_size; (void)out_size;

  float* outp = (float*)d_out;
  float* out_grd  = outp;                          // bs*LQ*C
  float* out_mhi  = outp + (size_t)MQ * kC;        // bs*LQ
  float* out_keep = out_mhi + (size_t)MQ;          // bs*LQ

  k_prep<<<1, 256, 0, stream>>>(Wout, bout, Wp, WoutWp, constWp);
  k_geom<<<(MQ + 255) / 256, 256, 0, stream>>>(camk, uv, out_keep, bs);
  gemm_f<0><<<dim3(4, (MV + 63) / 64), 256, 0, stream>>>(
      value, Wv, bv, nullptr, valp, MV, kC, kC);
  gemm16<<<dim3(4, (MQ + 15) / 16), 256, 0, stream>>>(query, Wo, bo, qoff,  MQ, 64, kC);
  gemm16<<<dim3(2, (MQ + 15) / 16), 256, 0, stream>>>(query, Wa, ba, qattn, MQ, 32, kC);
  gemm16<<<dim3(1, (MQ + 15) / 16), 256, 0, stream>>>(query, Wp, bp, qdot,  MQ, 1,  kC);
  k_fused<<<MQ / 4, 256, 0, stream>>>(valp, uv, qoff, qattn, qdot, WoutWp, constWp,
                                      msda_w, out_mhi);
  gemm_f<1><<<dim3(4, (MQ + 63) / 64), 256, 0, stream>>>(
      msda_w, Wout, bout, query, out_grd, MQ, kC, kC);
}

// Round 5
// 130.669 us; speedup vs baseline: 1.4263x; 1.2750x over previous
//
#include <hip/hip_runtime.h>
#include <hip/hip_bf16.h>

constexpr int kNV = 8;
constexpr int kHF = 26;
constexpr int kWF = 88;
constexpr int kC  = 256;
constexpr int kP  = 4;
constexpr int kNU = 33;
constexpr int kNH = 64;
constexpr int kLQ = kNU * kNH;   // 2112

// ---------------- prep: WoutWp = Wout@Wp, constWp = bout.Wp, Wcat/bcat -------------------
// Wcat[256][128]: cols 0-63 = Wo, 64-95 = Wa, 96 = Wp, 97-127 = 0
__global__ void k_prep(const float* __restrict__ Wout, const float* __restrict__ bout,
                       const float* __restrict__ Wp,   const float* __restrict__ bp,
                       const float* __restrict__ Wo,   const float* __restrict__ bo,
                       const float* __restrict__ Wa,   const float* __restrict__ ba,
                       float* __restrict__ WoutWp, float* __restrict__ constWp,
                       float* __restrict__ Wcat, float* __restrict__ bcat) {
  int tid = threadIdx.x;  // 256 threads, 1 block
  float s = 0.f;
  for (int j = 0; j < kC; ++j) s += Wout[(size_t)tid * kC + j] * Wp[j];
  WoutWp[tid] = s;

  __shared__ float red[256];
  red[tid] = bout[tid] * Wp[tid];
  __syncthreads();
  for (int off = 128; off > 0; off >>= 1) {
    if (tid < off) red[tid] += red[tid + off];
    __syncthreads();
  }
  if (tid == 0) constWp[0] = red[0];

  for (int idx = tid; idx < kC * 128; idx += 256) {
    int k = idx >> 7, c = idx & 127;
    float w = 0.f;
    if (c < 64)       w = Wo[k * 64 + c];
    else if (c < 96)  w = Wa[k * 32 + (c - 64)];
    else if (c == 96) w = Wp[k];
    Wcat[idx] = w;
  }
  if (tid < 128) {
    float bb = 0.f;
    if (tid < 64)       bb = bo[tid];
    else if (tid < 96)  bb = ba[tid - 64];
    else if (tid == 96) bb = bp[0];
    bcat[tid] = bb;
  }
}

// ---------------- geometry: uv in [bq][v][2] layout + keep_index ------------------------
__global__ void k_geom(const float* __restrict__ camk, float* __restrict__ uv,
                       float* __restrict__ out_keep, int bs) {
  int t = blockIdx.x * 256 + threadIdx.x;
  if (t >= bs * kLQ) return;
  int b = t / kLQ;
  int ij = t - b * kLQ;
  int i = ij / kNH;
  int j = ij - i * kNH;
  const float* K = camk + b * 9;
  float g0 = (float)(-25.6 + (double)j * (51.2 / 63.0));  //  y
  float g2 = (float)(25.6 - (double)i * 0.8);             // -x
  bool any = false;
  float* dst = uv + (size_t)t * 16;
  for (int k = 0; k < kNV; ++k) {
    float g1 = (float)(4.0 - (double)k * (8.0 / 7.0));    // -z
    float p0 = K[0] * g0 + K[1] * g1 + K[2] * g2;
    float p1 = K[3] * g0 + K[4] * g1 + K[5] * g2;
    float p2 = K[6] * g0 + K[7] * g1 + K[8] * g2;
    float den = (fabsf(p2) < 1e-6f) ? 1e-6f : p2;
    float u = p0 / den / 1408.0f;
    float v = p1 / den / 416.0f;
    any = any || (u >= 0.f && u <= 1.f && v >= 0.f && v <= 1.f);
    dst[k * 2]     = u;
    dst[k * 2 + 1] = v;
  }
  out_keep[t] = any ? 1.f : 0.f;
}

// ---------------- 32x64-tile fp32 GEMM, K-step 32, float4 loads --------------------------
// MODE 0: out = A@B + bias ; MODE 1: out = A@B + bias + 2*resid
// Requires K % 32 == 0, N % 64 == 0.
template <int MODE>
__global__ __launch_bounds__(256) void gemm32(
    const float* __restrict__ A, const float* __restrict__ B,
    const float* __restrict__ bias, const float* __restrict__ resid,
    float* __restrict__ out, int M, int N, int K) {
  __shared__ float As[32][36];
  __shared__ float Bs[32][64];
  int tid = threadIdx.x;
  int tx = tid & 15, ty = tid >> 4;
  int row0 = blockIdx.y * 32, col0 = blockIdx.x * 64;
  int ar = tid >> 3, ak = (tid & 7) * 4;   // A-tile: row, k-quad
  int bc = (tid & 15) * 4, bk = tid >> 4;  // B-tile: col-quad, k
  bool arow_ok = (row0 + ar) < M;
  const float* Ap = A + (size_t)(row0 + ar) * K + ak;
  float acc[2][4] = {};
  for (int k0 = 0; k0 < K; k0 += 32) {
    float4 a4 = {0.f, 0.f, 0.f, 0.f};
    if (arow_ok) a4 = *reinterpret_cast<const float4*>(Ap + k0);
    float4 b0 = *reinterpret_cast<const float4*>(&B[(size_t)(k0 + bk) * N + col0 + bc]);
    float4 b1 = *reinterpret_cast<const float4*>(&B[(size_t)(k0 + bk + 16) * N + col0 + bc]);
    __syncthreads();
    *reinterpret_cast<float4*>(&As[ar][ak]) = a4;
    *reinterpret_cast<float4*>(&Bs[bk][bc]) = b0;
    *reinterpret_cast<float4*>(&Bs[bk + 16][bc]) = b1;
    __syncthreads();
#pragma unroll
    for (int kk = 0; kk < 32; ++kk) {
      float a0 = As[ty * 2][kk];
      float a1 = As[ty * 2 + 1][kk];
      float4 b4 = *reinterpret_cast<const float4*>(&Bs[kk][tx * 4]);
      acc[0][0] += a0 * b4.x; acc[0][1] += a0 * b4.y;
      acc[0][2] += a0 * b4.z; acc[0][3] += a0 * b4.w;
      acc[1][0] += a1 * b4.x; acc[1][1] += a1 * b4.y;
      acc[1][2] += a1 * b4.z; acc[1][3] += a1 * b4.w;
    }
  }
  int gc = col0 + tx * 4;
  float4 bi = *reinterpret_cast<const float4*>(&bias[gc]);
#pragma unroll
  for (int i = 0; i < 2; ++i) {
    int gr = row0 + ty * 2 + i;
    if (gr >= M) continue;
    float4 r;
    r.x = acc[i][0] + bi.x; r.y = acc[i][1] + bi.y;
    r.z = acc[i][2] + bi.z; r.w = acc[i][3] + bi.w;
    if (MODE == 1) {
      float4 q4 = *reinterpret_cast<const float4*>(&resid[(size_t)gr * N + gc]);
      r.x += 2.f * q4.x; r.y += 2.f * q4.y; r.z += 2.f * q4.z; r.w += 2.f * q4.w;
    }
    *reinterpret_cast<float4*>(&out[(size_t)gr * N + gc]) = r;
  }
}

// ---------------- fused sampling: one wave per (b,q) -------------------------------------
// lane l: head h = l>>3, channels h*32 + (l&7)*4 .. +3 (float4)
__global__ __launch_bounds__(256) void k_fused(
    const float* __restrict__ valp, const float* __restrict__ uv,
    const float* __restrict__ qcat, const float* __restrict__ WoutWp,
    const float* __restrict__ constWp,
    float* __restrict__ msda_w, float* __restrict__ out_mhi) {
  int wid = threadIdx.x >> 6;
  int lane = threadIdx.x & 63;
  int bq = blockIdx.x * 4 + wid;
  int b = bq / kLQ;
  int h = lane >> 3;
  int dq = lane & 7;
  int ch = h * 32 + dq * 4;

  const float* qp = qcat + (size_t)bq * 128;

  // attention softmax over P for this head
  float4 qa4 = *reinterpret_cast<const float4*>(qp + 64 + h * 4);
  float am = fmaxf(fmaxf(qa4.x, qa4.y), fmaxf(qa4.z, qa4.w));
  float e0 = expf(qa4.x - am), e1 = expf(qa4.y - am);
  float e2 = expf(qa4.z - am), e3 = expf(qa4.w - am);
  float ei = 1.f / (e0 + e1 + e2 + e3);
  float aw[4] = {e0 * ei, e1 * ei, e2 * ei, e3 * ei};

  float4 qo0 = *reinterpret_cast<const float4*>(qp + h * 8);
  float4 qo1 = *reinterpret_cast<const float4*>(qp + h * 8 + 4);
  float offx[4] = {qo0.x, qo0.z, qo1.x, qo1.z};
  float offy[4] = {qo0.y, qo0.w, qo1.y, qo1.w};

  // all 8 view (u,v) pairs up front
  float ub[kNV], vb[kNV];
  const float4* uvp = reinterpret_cast<const float4*>(uv + (size_t)bq * 16);
#pragma unroll
  for (int i = 0; i < 4; ++i) {
    float4 t = uvp[i];
    ub[2 * i]     = t.x * 88.0f - 0.5f;
    vb[2 * i]     = t.y * 26.0f - 0.5f;
    ub[2 * i + 1] = t.z * 88.0f - 0.5f;
    vb[2 * i + 1] = t.w * 26.0f - 0.5f;
  }

  const float* vp = valp + (size_t)b * (kHF * kWF) * kC + ch;
  float4 w4 = *reinterpret_cast<const float4*>(WoutWp + ch);

  float4 sv[kNV];
  float lg[kNV];

#pragma unroll
  for (int v = 0; v < kNV; ++v) {
    float4 s4 = {0.f, 0.f, 0.f, 0.f};
#pragma unroll
    for (int p = 0; p < kP; ++p) {
      float px = ub[v] + offx[p];
      float py = vb[v] + offy[p];
      px = fminf(fmaxf(px, -10000.f), 10000.f);
      py = fminf(fmaxf(py, -10000.f), 10000.f);
      float x0f = floorf(px), y0f = floorf(py);
      float lx = px - x0f, ly = py - y0f;
      int x0 = (int)x0f, y0 = (int)y0f;
#pragma unroll
      for (int cy = 0; cy < 2; ++cy) {
#pragma unroll
        for (int cx = 0; cx < 2; ++cx) {
          int xi = x0 + cx, yi = y0 + cy;
          float w = (cx ? lx : 1.f - lx) * (cy ? ly : 1.f - ly) * aw[p];
          bool valid = (xi >= 0) && (xi < kWF) && (yi >= 0) && (yi < kHF);
          int xc = xi < 0 ? 0 : (xi > kWF - 1 ? kWF - 1 : xi);
          int yc = yi < 0 ? 0 : (yi > kHF - 1 ? kHF - 1 : yi);
          float4 g = *reinterpret_cast<const float4*>(vp + (size_t)(yc * kWF + xc) * kC);
          float wv = valid ? w : 0.f;
          s4.x += wv * g.x; s4.y += wv * g.y; s4.z += wv * g.z; s4.w += wv * g.w;
        }
      }
    }
    sv[v] = s4;
    float lv = s4.x * w4.x + s4.y * w4.y + s4.z * w4.z + s4.w * w4.w;
#pragma unroll
    for (int o = 32; o > 0; o >>= 1) lv += __shfl_down(lv, o, 64);
    lg[v] = lv;  // true value in lane 0 only
  }

  float wk[kNV];
  if (lane == 0) {
    float qd = qp[96] + constWp[0];
    float m = -1e30f; int ai = 0;
#pragma unroll
    for (int v = 0; v < kNV; ++v) {
      lg[v] += qd;
      if (lg[v] > m) { m = lg[v]; ai = v; }
    }
    float ssum = 0.f;
#pragma unroll
    for (int v = 0; v < kNV; ++v) { wk[v] = expf(lg[v] - m); ssum += wk[v]; }
    float invs = 1.f / ssum;
#pragma unroll
    for (int v = 0; v < kNV; ++v) wk[v] *= invs;
    out_mhi[bq] = (float)ai;
  }
  float4 acc = {0.f, 0.f, 0.f, 0.f};
#pragma unroll
  for (int v = 0; v < kNV; ++v) {
    float wv = __shfl(wk[v], 0, 64);
    acc.x += wv * sv[v].x; acc.y += wv * sv[v].y;
    acc.z += wv * sv[v].z; acc.w += wv * sv[v].w;
  }
  *reinterpret_cast<float4*>(msda_w + (size_t)bq * kC + ch) = acc;
}

extern "C" void kernel_launch(void* const* d_in, const int* in_sizes, int n_in,
                              void* d_out, int out_size, void* d_ws, size_t ws_size,
                              hipStream_t stream) {
  if (n_in < 13) return;
  const float* query = (const float*)d_in[0];
  const float* value = (const float*)d_in[1];
  const float* camk  = (const float*)d_in[2];
  const float* Wv    = (const float*)d_in[3];
  const float* bv    = (const float*)d_in[4];
  const float* Wo    = (const float*)d_in[5];
  const float* bo    = (const float*)d_in[6];
  const float* Wa    = (const float*)d_in[7];
  const float* ba    = (const float*)d_in[8];
  const float* Wout  = (const float*)d_in[9];
  const float* bout  = (const float*)d_in[10];
  const float* Wp    = (const float*)d_in[11];
  const float* bp    = (const float*)d_in[12];
  int bs = in_sizes[0] / (kLQ * kC);
  int MQ = bs * kLQ;          // 4224
  int MV = bs * kHF * kWF;    // 4576

  float* ws = (float*)d_ws;
  size_t o = 0;
  float* valp    = ws + o; o += (size_t)MV * kC;
  float* uv      = ws + o; o += (size_t)MQ * 16;
  float* qcat    = ws + o; o += (size_t)MQ * 128;
  float* msda_w  = ws + o; o += (size_t)MQ * kC;
  float* WoutWp  = ws + o; o += kC;
  float* constWp = ws + o; o += 1;
  float* Wcat    = ws + o; o += kC * 128;
  float* bcat    = ws + o; o += 128;
  (void)ws_size; (void)out_size;

  float* outp = (float*)d_out;
  float* out_grd  = outp;                          // bs*LQ*C
  float* out_mhi  = outp + (size_t)MQ * kC;        // bs*LQ
  float* out_keep = out_mhi + (size_t)MQ;          // bs*LQ

  k_prep<<<1, 256, 0, stream>>>(Wout, bout, Wp, bp, Wo, bo, Wa, ba,
                                WoutWp, constWp, Wcat, bcat);
  k_geom<<<(MQ + 255) / 256, 256, 0, stream>>>(camk, uv, out_keep, bs);
  gemm32<0><<<dim3(kC / 64, (MV + 31) / 32), 256, 0, stream>>>(
      value, Wv, bv, nullptr, valp, MV, kC, kC);
  gemm32<0><<<dim3(128 / 64, (MQ + 31) / 32), 256, 0, stream>>>(
      query, Wcat, bcat, nullptr, qcat, MQ, 128, kC);
  k_fused<<<MQ / 4, 256, 0, stream>>>(valp, uv, qcat, WoutWp, constWp,
                                      msda_w, out_mhi);
  gemm32<1><<<dim3(kC / 64, (MQ + 31) / 32), 256, 0, stream>>>(
      msda_w, Wout, bout, query, out_grd, MQ, kC, kC);
}

// Round 6
// 87.137 us; speedup vs baseline: 2.1388x; 1.4996x over previous
//
#include <hip/hip_runtime.h>
#include <hip/hip_bf16.h>

constexpr int kNV = 8;
constexpr int kHF = 26;
constexpr int kWF = 88;
constexpr int kC  = 256;
constexpr int kP  = 4;
constexpr int kNU = 33;
constexpr int kNH = 64;
constexpr int kLQ = kNU * kNH;   // 2112

// ---------------- prep A: WoutWp[r] = Wout[r,:].Wp (block r), constWp (block 256) -------
__global__ __launch_bounds__(64) void k_prep_wp(
    const float* __restrict__ Wout, const float* __restrict__ bout,
    const float* __restrict__ Wp,
    float* __restrict__ WoutWp, float* __restrict__ constWp) {
  int r = blockIdx.x;
  int lane = threadIdx.x;
  const float* row = (r < kC) ? (Wout + (size_t)r * kC) : bout;
  float s = 0.f;
#pragma unroll
  for (int j = lane; j < kC; j += 64) s += row[j] * Wp[j];
#pragma unroll
  for (int o = 32; o > 0; o >>= 1) s += __shfl_down(s, o, 64);
  if (lane == 0) {
    if (r < kC) WoutWp[r] = s;
    else        constWp[0] = s;
  }
}

// ---------------- prep B: Wcat[256][128] = [Wo | Wa | Wp | 0], bcat --------------------
__global__ __launch_bounds__(256) void k_cat(
    const float* __restrict__ Wo, const float* __restrict__ bo,
    const float* __restrict__ Wa, const float* __restrict__ ba,
    const float* __restrict__ Wp, const float* __restrict__ bp,
    float* __restrict__ Wcat, float* __restrict__ bcat) {
  int idx = blockIdx.x * 256 + threadIdx.x;   // [0, 32768)
  int k = idx >> 7, c = idx & 127;
  float w = 0.f;
  if (c < 64)       w = Wo[k * 64 + c];
  else if (c < 96)  w = Wa[k * 32 + (c - 64)];
  else if (c == 96) w = Wp[k];
  Wcat[idx] = w;
  if (blockIdx.x == 0 && threadIdx.x < 128) {
    int t = threadIdx.x;
    float bb = 0.f;
    if (t < 64)       bb = bo[t];
    else if (t < 96)  bb = ba[t - 64];
    else if (t == 96) bb = bp[0];
    bcat[t] = bb;
  }
}

// ---------------- geometry: uv in [bq][v][2] layout + keep_index ------------------------
__global__ void k_geom(const float* __restrict__ camk, float* __restrict__ uv,
                       float* __restrict__ out_keep, int bs) {
  int t = blockIdx.x * 256 + threadIdx.x;
  if (t >= bs * kLQ) return;
  int b = t / kLQ;
  int ij = t - b * kLQ;
  int i = ij / kNH;
  int j = ij - i * kNH;
  const float* K = camk + b * 9;
  float g0 = (float)(-25.6 + (double)j * (51.2 / 63.0));  //  y
  float g2 = (float)(25.6 - (double)i * 0.8);             // -x
  bool any = false;
  float* dst = uv + (size_t)t * 16;
  for (int k = 0; k < kNV; ++k) {
    float g1 = (float)(4.0 - (double)k * (8.0 / 7.0));    // -z
    float p0 = K[0] * g0 + K[1] * g1 + K[2] * g2;
    float p1 = K[3] * g0 + K[4] * g1 + K[5] * g2;
    float p2 = K[6] * g0 + K[7] * g1 + K[8] * g2;
    float den = (fabsf(p2) < 1e-6f) ? 1e-6f : p2;
    float u = p0 / den / 1408.0f;
    float v = p1 / den / 416.0f;
    any = any || (u >= 0.f && u <= 1.f && v >= 0.f && v <= 1.f);
    dst[k * 2]     = u;
    dst[k * 2 + 1] = v;
  }
  out_keep[t] = any ? 1.f : 0.f;
}

// ---------------- 32x64-tile fp32 GEMM, K-step 32, float4 loads --------------------------
// MODE 0: out = A@B + bias ; MODE 1: out = A@B + bias + 2*resid
// Requires K % 32 == 0, N % 64 == 0.
template <int MODE>
__global__ __launch_bounds__(256) void gemm32(
    const float* __restrict__ A, const float* __restrict__ B,
    const float* __restrict__ bias, const float* __restrict__ resid,
    float* __restrict__ out, int M, int N, int K) {
  __shared__ float As[32][36];
  __shared__ float Bs[32][64];
  int tid = threadIdx.x;
  int tx = tid & 15, ty = tid >> 4;
  int row0 = blockIdx.y * 32, col0 = blockIdx.x * 64;
  int ar = tid >> 3, ak = (tid & 7) * 4;   // A-tile: row, k-quad
  int bc = (tid & 15) * 4, bk = tid >> 4;  // B-tile: col-quad, k
  bool arow_ok = (row0 + ar) < M;
  const float* Ap = A + (size_t)(row0 + ar) * K + ak;
  float acc[2][4] = {};
  for (int k0 = 0; k0 < K; k0 += 32) {
    float4 a4 = {0.f, 0.f, 0.f, 0.f};
    if (arow_ok) a4 = *reinterpret_cast<const float4*>(Ap + k0);
    float4 b0 = *reinterpret_cast<const float4*>(&B[(size_t)(k0 + bk) * N + col0 + bc]);
    float4 b1 = *reinterpret_cast<const float4*>(&B[(size_t)(k0 + bk + 16) * N + col0 + bc]);
    __syncthreads();
    *reinterpret_cast<float4*>(&As[ar][ak]) = a4;
    *reinterpret_cast<float4*>(&Bs[bk][bc]) = b0;
    *reinterpret_cast<float4*>(&Bs[bk + 16][bc]) = b1;
    __syncthreads();
#pragma unroll
    for (int kk = 0; kk < 32; ++kk) {
      float a0 = As[ty * 2][kk];
      float a1 = As[ty * 2 + 1][kk];
      float4 b4 = *reinterpret_cast<const float4*>(&Bs[kk][tx * 4]);
      acc[0][0] += a0 * b4.x; acc[0][1] += a0 * b4.y;
      acc[0][2] += a0 * b4.z; acc[0][3] += a0 * b4.w;
      acc[1][0] += a1 * b4.x; acc[1][1] += a1 * b4.y;
      acc[1][2] += a1 * b4.z; acc[1][3] += a1 * b4.w;
    }
  }
  int gc = col0 + tx * 4;
  float4 bi = *reinterpret_cast<const float4*>(&bias[gc]);
#pragma unroll
  for (int i = 0; i < 2; ++i) {
    int gr = row0 + ty * 2 + i;
    if (gr >= M) continue;
    float4 r;
    r.x = acc[i][0] + bi.x; r.y = acc[i][1] + bi.y;
    r.z = acc[i][2] + bi.z; r.w = acc[i][3] + bi.w;
    if (MODE == 1) {
      float4 q4 = *reinterpret_cast<const float4*>(&resid[(size_t)gr * N + gc]);
      r.x += 2.f * q4.x; r.y += 2.f * q4.y; r.z += 2.f * q4.z; r.w += 2.f * q4.w;
    }
    *reinterpret_cast<float4*>(&out[(size_t)gr * N + gc]) = r;
  }
}

// ---------------- fused sampling: one wave per (b,q) -------------------------------------
// lane l: head h = l>>3, channels h*32 + (l&7)*4 .. +3 (float4)
__global__ __launch_bounds__(256) void k_fused(
    const float* __restrict__ valp, const float* __restrict__ uv,
    const float* __restrict__ qcat, const float* __restrict__ WoutWp,
    const float* __restrict__ constWp,
    float* __restrict__ msda_w, float* __restrict__ out_mhi) {
  int wid = threadIdx.x >> 6;
  int lane = threadIdx.x & 63;
  int bq = blockIdx.x * 4 + wid;
  int b = bq / kLQ;
  int h = lane >> 3;
  int dq = lane & 7;
  int ch = h * 32 + dq * 4;

  const float* qp = qcat + (size_t)bq * 128;

  // attention softmax over P for this head
  float4 qa4 = *reinterpret_cast<const float4*>(qp + 64 + h * 4);
  float am = fmaxf(fmaxf(qa4.x, qa4.y), fmaxf(qa4.z, qa4.w));
  float e0 = expf(qa4.x - am), e1 = expf(qa4.y - am);
  float e2 = expf(qa4.z - am), e3 = expf(qa4.w - am);
  float ei = 1.f / (e0 + e1 + e2 + e3);
  float aw[4] = {e0 * ei, e1 * ei, e2 * ei, e3 * ei};

  float4 qo0 = *reinterpret_cast<const float4*>(qp + h * 8);
  float4 qo1 = *reinterpret_cast<const float4*>(qp + h * 8 + 4);
  float offx[4] = {qo0.x, qo0.z, qo1.x, qo1.z};
  float offy[4] = {qo0.y, qo0.w, qo1.y, qo1.w};

  // all 8 view (u,v) pairs up front
  float ub[kNV], vb[kNV];
  const float4* uvp = reinterpret_cast<const float4*>(uv + (size_t)bq * 16);
#pragma unroll
  for (int i = 0; i < 4; ++i) {
    float4 t = uvp[i];
    ub[2 * i]     = t.x * 88.0f - 0.5f;
    vb[2 * i]     = t.y * 26.0f - 0.5f;
    ub[2 * i + 1] = t.z * 88.0f - 0.5f;
    vb[2 * i + 1] = t.w * 26.0f - 0.5f;
  }

  const float* vp = valp + (size_t)b * (kHF * kWF) * kC + ch;
  float4 w4 = *reinterpret_cast<const float4*>(WoutWp + ch);

  float4 sv[kNV];
  float lg[kNV];

#pragma unroll
  for (int v = 0; v < kNV; ++v) {
    float4 s4 = {0.f, 0.f, 0.f, 0.f};
#pragma unroll
    for (int p = 0; p < kP; ++p) {
      float px = ub[v] + offx[p];
      float py = vb[v] + offy[p];
      px = fminf(fmaxf(px, -10000.f), 10000.f);
      py = fminf(fmaxf(py, -10000.f), 10000.f);
      float x0f = floorf(px), y0f = floorf(py);
      float lx = px - x0f, ly = py - y0f;
      int x0 = (int)x0f, y0 = (int)y0f;
#pragma unroll
      for (int cy = 0; cy < 2; ++cy) {
#pragma unroll
        for (int cx = 0; cx < 2; ++cx) {
          int xi = x0 + cx, yi = y0 + cy;
          float w = (cx ? lx : 1.f - lx) * (cy ? ly : 1.f - ly) * aw[p];
          bool valid = (xi >= 0) && (xi < kWF) && (yi >= 0) && (yi < kHF);
          int xc = xi < 0 ? 0 : (xi > kWF - 1 ? kWF - 1 : xi);
          int yc = yi < 0 ? 0 : (yi > kHF - 1 ? kHF - 1 : yi);
          float4 g = *reinterpret_cast<const float4*>(vp + (size_t)(yc * kWF + xc) * kC);
          float wv = valid ? w : 0.f;
          s4.x += wv * g.x; s4.y += wv * g.y; s4.z += wv * g.z; s4.w += wv * g.w;
        }
      }
    }
    sv[v] = s4;
    float lv = s4.x * w4.x + s4.y * w4.y + s4.z * w4.z + s4.w * w4.w;
#pragma unroll
    for (int o = 32; o > 0; o >>= 1) lv += __shfl_down(lv, o, 64);
    lg[v] = lv;  // true value in lane 0 only
  }

  float wk[kNV];
  if (lane == 0) {
    float qd = qp[96] + constWp[0];
    float m = -1e30f; int ai = 0;
#pragma unroll
    for (int v = 0; v < kNV; ++v) {
      lg[v] += qd;
      if (lg[v] > m) { m = lg[v]; ai = v; }
    }
    float ssum = 0.f;
#pragma unroll
    for (int v = 0; v < kNV; ++v) { wk[v] = expf(lg[v] - m); ssum += wk[v]; }
    float invs = 1.f / ssum;
#pragma unroll
    for (int v = 0; v < kNV; ++v) wk[v] *= invs;
    out_mhi[bq] = (float)ai;
  }
  float4 acc = {0.f, 0.f, 0.f, 0.f};
#pragma unroll
  for (int v = 0; v < kNV; ++v) {
    float wv = __shfl(wk[v], 0, 64);
    acc.x += wv * sv[v].x; acc.y += wv * sv[v].y;
    acc.z += wv * sv[v].z; acc.w += wv * sv[v].w;
  }
  *reinterpret_cast<float4*>(msda_w + (size_t)bq * kC + ch) = acc;
}

extern "C" void kernel_launch(void* const* d_in, const int* in_sizes, int n_in,
                              void* d_out, int out_size, void* d_ws, size_t ws_size,
                              hipStream_t stream) {
  if (n_in < 13) return;
  const float* query = (const float*)d_in[0];
  const float* value = (const float*)d_in[1];
  const float* camk  = (const float*)d_in[2];
  const float* Wv    = (const float*)d_in[3];
  const float* bv    = (const float*)d_in[4];
  const float* Wo    = (const float*)d_in[5];
  const float* bo    = (const float*)d_in[6];
  const float* Wa    = (const float*)d_in[7];
  const float* ba    = (const float*)d_in[8];
  const float* Wout  = (const float*)d_in[9];
  const float* bout  = (const float*)d_in[10];
  const float* Wp    = (const float*)d_in[11];
  const float* bp    = (const float*)d_in[12];
  int bs = in_sizes[0] / (kLQ * kC);
  int MQ = bs * kLQ;          // 4224
  int MV = bs * kHF * kWF;    // 4576

  float* ws = (float*)d_ws;
  size_t o = 0;
  float* valp    = ws + o; o += (size_t)MV * kC;
  float* uv      = ws + o; o += (size_t)MQ * 16;
  float* qcat    = ws + o; o += (size_t)MQ * 128;
  float* msda_w  = ws + o; o += (size_t)MQ * kC;
  float* WoutWp  = ws + o; o += kC;
  float* constWp = ws + o; o += 1;
  float* Wcat    = ws + o; o += kC * 128;
  float* bcat    = ws + o; o += 128;
  (void)ws_size; (void)out_size;

  float* outp = (float*)d_out;
  float* out_grd  = outp;                          // bs*LQ*C
  float* out_mhi  = outp + (size_t)MQ * kC;        // bs*LQ
  float* out_keep = out_mhi + (size_t)MQ;          // bs*LQ

  k_prep_wp<<<kC + 1, 64, 0, stream>>>(Wout, bout, Wp, WoutWp, constWp);
  k_cat<<<kC * 128 / 256, 256, 0, stream>>>(Wo, bo, Wa, ba, Wp, bp, Wcat, bcat);
  k_geom<<<(MQ + 255) / 256, 256, 0, stream>>>(camk, uv, out_keep, bs);
  gemm32<0><<<dim3(kC / 64, (MV + 31) / 32), 256, 0, stream>>>(
      value, Wv, bv, nullptr, valp, MV, kC, kC);
  gemm32<0><<<dim3(128 / 64, (MQ + 31) / 32), 256, 0, stream>>>(
      query, Wcat, bcat, nullptr, qcat, MQ, 128, kC);
  k_fused<<<MQ / 4, 256, 0, stream>>>(valp, uv, qcat, WoutWp, constWp,
                                      msda_w, out_mhi);
  gemm32<1><<<dim3(kC / 64, (MQ + 31) / 32), 256, 0, stream>>>(
      msda_w, Wout, bout, query, out_grd, MQ, kC, kC);
}

// Round 7
// 74.571 us; speedup vs baseline: 2.4993x; 1.1685x over previous
//
#include <hip/hip_runtime.h>
#include <hip/hip_bf16.h>

constexpr int kNV = 8;
constexpr int kHF = 26;
constexpr int kWF = 88;
constexpr int kC  = 256;
constexpr int kP  = 4;
constexpr int kNU = 33;
constexpr int kNH = 64;
constexpr int kLQ = kNU * kNH;   // 2112

// ---------------- setup: geometry + Wcat/bcat + WoutWp in ONE launch --------------------
// blocks [0, nGeomBlk)            : uv + keep_index
// blocks [nGeomBlk, nGeomBlk+128) : Wcat[256][128] = [Wo | Wa | 0], bcat
// blocks [nGeomBlk+128, +64)      : WoutWp[r] = Wout[r,:].Wp  (4 rows per block)
__global__ __launch_bounds__(256) void k_setup(
    const float* __restrict__ camk,
    const float* __restrict__ Wout, const float* __restrict__ Wp,
    const float* __restrict__ Wo,   const float* __restrict__ bo,
    const float* __restrict__ Wa,   const float* __restrict__ ba,
    float* __restrict__ uv, float* __restrict__ out_keep,
    float* __restrict__ WoutWp, float* __restrict__ Wcat,
    float* __restrict__ bcat, int bs, int nGeomBlk) {
  int blk = blockIdx.x;
  int tid = threadIdx.x;
  if (blk < nGeomBlk) {
    int t = blk * 256 + tid;
    if (t >= bs * kLQ) return;
    int b = t / kLQ;
    int ij = t - b * kLQ;
    int i = ij / kNH;
    int j = ij - i * kNH;
    const float* K = camk + b * 9;
    float g0 = (float)(-25.6 + (double)j * (51.2 / 63.0));  //  y
    float g2 = (float)(25.6 - (double)i * 0.8);             // -x
    bool any = false;
    float* dst = uv + (size_t)t * 16;
    for (int k = 0; k < kNV; ++k) {
      float g1 = (float)(4.0 - (double)k * (8.0 / 7.0));    // -z
      float p0 = K[0] * g0 + K[1] * g1 + K[2] * g2;
      float p1 = K[3] * g0 + K[4] * g1 + K[5] * g2;
      float p2 = K[6] * g0 + K[7] * g1 + K[8] * g2;
      float den = (fabsf(p2) < 1e-6f) ? 1e-6f : p2;
      float u = p0 / den / 1408.0f;
      float v = p1 / den / 416.0f;
      any = any || (u >= 0.f && u <= 1.f && v >= 0.f && v <= 1.f);
      dst[k * 2]     = u;
      dst[k * 2 + 1] = v;
    }
    out_keep[t] = any ? 1.f : 0.f;
  } else if (blk < nGeomBlk + 128) {
    int idx = (blk - nGeomBlk) * 256 + tid;   // [0, 32768)
    int k = idx >> 7, c = idx & 127;
    float w = 0.f;
    if (c < 64)      w = Wo[k * 64 + c];
    else if (c < 96) w = Wa[k * 32 + (c - 64)];
    Wcat[idx] = w;
    if (idx < 128) {
      float bb = 0.f;
      if (idx < 64)      bb = bo[idx];
      else if (idx < 96) bb = ba[idx - 64];
      bcat[idx] = bb;
    }
  } else {
    int r = (blk - nGeomBlk - 128) * 4 + (tid >> 6);
    int lane = tid & 63;
    const float* row = Wout + (size_t)r * kC;
    float s = 0.f;
#pragma unroll
    for (int j = lane; j < kC; j += 64) s += row[j] * Wp[j];
#pragma unroll
    for (int o = 32; o > 0; o >>= 1) s += __shfl_down(s, o, 64);
    if (lane == 0) WoutWp[r] = s;
  }
}

// ---------------- 32x64-tile fp32 GEMM body, K-step 32, float4 loads --------------------
// MODE 0: out = A@B + bias ; MODE 1: out = A@B + bias + 2*resid
// Requires K % 32 == 0, N % 64 == 0.
template <int MODE>
__device__ __forceinline__ void gemm_body(
    const float* __restrict__ A, const float* __restrict__ B,
    const float* __restrict__ bias, const float* __restrict__ resid,
    float* __restrict__ out, int M, int N, int K, int bx, int by) {
  __shared__ float As[32][36];
  __shared__ float Bs[32][64];
  int tid = threadIdx.x;
  int tx = tid & 15, ty = tid >> 4;
  int row0 = by * 32, col0 = bx * 64;
  int ar = tid >> 3, ak = (tid & 7) * 4;   // A-tile: row, k-quad
  int bc = (tid & 15) * 4, bk = tid >> 4;  // B-tile: col-quad, k
  bool arow_ok = (row0 + ar) < M;
  const float* Ap = A + (size_t)(row0 + ar) * K + ak;
  float acc[2][4] = {};
  for (int k0 = 0; k0 < K; k0 += 32) {
    float4 a4 = {0.f, 0.f, 0.f, 0.f};
    if (arow_ok) a4 = *reinterpret_cast<const float4*>(Ap + k0);
    float4 b0 = *reinterpret_cast<const float4*>(&B[(size_t)(k0 + bk) * N + col0 + bc]);
    float4 b1 = *reinterpret_cast<const float4*>(&B[(size_t)(k0 + bk + 16) * N + col0 + bc]);
    __syncthreads();
    *reinterpret_cast<float4*>(&As[ar][ak]) = a4;
    *reinterpret_cast<float4*>(&Bs[bk][bc]) = b0;
    *reinterpret_cast<float4*>(&Bs[bk + 16][bc]) = b1;
    __syncthreads();
#pragma unroll
    for (int kk = 0; kk < 32; ++kk) {
      float a0 = As[ty * 2][kk];
      float a1 = As[ty * 2 + 1][kk];
      float4 b4 = *reinterpret_cast<const float4*>(&Bs[kk][tx * 4]);
      acc[0][0] += a0 * b4.x; acc[0][1] += a0 * b4.y;
      acc[0][2] += a0 * b4.z; acc[0][3] += a0 * b4.w;
      acc[1][0] += a1 * b4.x; acc[1][1] += a1 * b4.y;
      acc[1][2] += a1 * b4.z; acc[1][3] += a1 * b4.w;
    }
  }
  int gc = col0 + tx * 4;
  float4 bi = *reinterpret_cast<const float4*>(&bias[gc]);
#pragma unroll
  for (int i = 0; i < 2; ++i) {
    int gr = row0 + ty * 2 + i;
    if (gr >= M) continue;
    float4 r;
    r.x = acc[i][0] + bi.x; r.y = acc[i][1] + bi.y;
    r.z = acc[i][2] + bi.z; r.w = acc[i][3] + bi.w;
    if (MODE == 1) {
      float4 q4 = *reinterpret_cast<const float4*>(&resid[(size_t)gr * N + gc]);
      r.x += 2.f * q4.x; r.y += 2.f * q4.y; r.z += 2.f * q4.z; r.w += 2.f * q4.w;
    }
    *reinterpret_cast<float4*>(&out[(size_t)gr * N + gc]) = r;
  }
}

// two independent MODE-0 GEMM problems in one dispatch (better CU fill)
__global__ __launch_bounds__(256) void gemm_dual(
    const float* __restrict__ A0, const float* __restrict__ B0,
    const float* __restrict__ bias0, float* __restrict__ out0,
    int M0, int N0, int K0, int yb0,
    const float* __restrict__ A1, const float* __restrict__ B1,
    const float* __restrict__ bias1, float* __restrict__ out1,
    int M1, int N1, int K1, int xb1) {
  if ((int)blockIdx.y < yb0) {
    gemm_body<0>(A0, B0, bias0, nullptr, out0, M0, N0, K0, blockIdx.x, blockIdx.y);
  } else {
    if ((int)blockIdx.x >= xb1) return;
    gemm_body<0>(A1, B1, bias1, nullptr, out1, M1, N1, K1, blockIdx.x,
                 blockIdx.y - yb0);
  }
}

__global__ __launch_bounds__(256) void gemm_res(
    const float* __restrict__ A, const float* __restrict__ B,
    const float* __restrict__ bias, const float* __restrict__ resid,
    float* __restrict__ out, int M, int N, int K) {
  gemm_body<1>(A, B, bias, resid, out, M, N, K, blockIdx.x, blockIdx.y);
}

// ---------------- fused sampling: 2 waves per (b,q), 4 views per wave --------------------
// lane l: head h = l>>3, channels h*32 + (l&7)*4 .. +3 (float4)
__global__ __launch_bounds__(128) void k_fused(
    const float* __restrict__ valp, const float* __restrict__ uv,
    const float* __restrict__ qcat, const float* __restrict__ WoutWp,
    float* __restrict__ msda_w, float* __restrict__ out_mhi) {
  int bq = blockIdx.x;
  int b = bq / kLQ;
  int tid = threadIdx.x;
  int wp = tid >> 6;        // wave 0: v=0..3, wave 1: v=4..7
  int lane = tid & 63;
  int h = lane >> 3;
  int dq = lane & 7;
  int ch = h * 32 + dq * 4;

  const float* qp = qcat + (size_t)bq * 128;

  // attention softmax over P for this head
  float4 qa4 = *reinterpret_cast<const float4*>(qp + 64 + h * 4);
  float am = fmaxf(fmaxf(qa4.x, qa4.y), fmaxf(qa4.z, qa4.w));
  float e0 = expf(qa4.x - am), e1 = expf(qa4.y - am);
  float e2 = expf(qa4.z - am), e3 = expf(qa4.w - am);
  float ei = 1.f / (e0 + e1 + e2 + e3);
  float aw[4] = {e0 * ei, e1 * ei, e2 * ei, e3 * ei};

  float4 qo0 = *reinterpret_cast<const float4*>(qp + h * 8);
  float4 qo1 = *reinterpret_cast<const float4*>(qp + h * 8 + 4);
  float offx[4] = {qo0.x, qo0.z, qo1.x, qo1.z};
  float offy[4] = {qo0.y, qo0.w, qo1.y, qo1.w};

  // this wave's 4 view (u,v) pairs
  float ub[4], vb[4];
  const float4* uvp = reinterpret_cast<const float4*>(uv + (size_t)bq * 16) + wp * 2;
#pragma unroll
  for (int i = 0; i < 2; ++i) {
    float4 t = uvp[i];
    ub[2 * i]     = t.x * 88.0f - 0.5f;
    vb[2 * i]     = t.y * 26.0f - 0.5f;
    ub[2 * i + 1] = t.z * 88.0f - 0.5f;
    vb[2 * i + 1] = t.w * 26.0f - 0.5f;
  }

  const float* vp = valp + (size_t)b * (kHF * kWF) * kC + ch;
  float4 w4 = *reinterpret_cast<const float4*>(WoutWp + ch);

  __shared__ float lgs[kNV];
  __shared__ float wks[kNV];
  __shared__ float4 part[64];

  float4 sv[4];
#pragma unroll
  for (int vv = 0; vv < 4; ++vv) {
    float4 s4 = {0.f, 0.f, 0.f, 0.f};
#pragma unroll
    for (int p = 0; p < kP; ++p) {
      float px = ub[vv] + offx[p];
      float py = vb[vv] + offy[p];
      px = fminf(fmaxf(px, -10000.f), 10000.f);
      py = fminf(fmaxf(py, -10000.f), 10000.f);
      float x0f = floorf(px), y0f = floorf(py);
      float lx = px - x0f, ly = py - y0f;
      int x0 = (int)x0f, y0 = (int)y0f;
#pragma unroll
      for (int cy = 0; cy < 2; ++cy) {
#pragma unroll
        for (int cx = 0; cx < 2; ++cx) {
          int xi = x0 + cx, yi = y0 + cy;
          float w = (cx ? lx : 1.f - lx) * (cy ? ly : 1.f - ly) * aw[p];
          bool valid = (xi >= 0) && (xi < kWF) && (yi >= 0) && (yi < kHF);
          int xc = xi < 0 ? 0 : (xi > kWF - 1 ? kWF - 1 : xi);
          int yc = yi < 0 ? 0 : (yi > kHF - 1 ? kHF - 1 : yi);
          float4 g = *reinterpret_cast<const float4*>(vp + (size_t)(yc * kWF + xc) * kC);
          float wv = valid ? w : 0.f;
          s4.x += wv * g.x; s4.y += wv * g.y; s4.z += wv * g.z; s4.w += wv * g.w;
        }
      }
    }
    sv[vv] = s4;
    float lv = s4.x * w4.x + s4.y * w4.y + s4.z * w4.z + s4.w * w4.w;
#pragma unroll
    for (int o = 32; o > 0; o >>= 1) lv += __shfl_down(lv, o, 64);
    if (lane == 0) lgs[wp * 4 + vv] = lv;
  }
  __syncthreads();
  if (tid == 0) {
    // height softmax + argmax (v-independent constant terms cancel exactly)
    float m = -1e30f; int ai = 0;
#pragma unroll
    for (int v = 0; v < kNV; ++v)
      if (lgs[v] > m) { m = lgs[v]; ai = v; }
    float ssum = 0.f;
    float ev[kNV];
#pragma unroll
    for (int v = 0; v < kNV; ++v) { ev[v] = expf(lgs[v] - m); ssum += ev[v]; }
    float invs = 1.f / ssum;
#pragma unroll
    for (int v = 0; v < kNV; ++v) wks[v] = ev[v] * invs;
    out_mhi[bq] = (float)ai;
  }
  __syncthreads();
  float4 acc = {0.f, 0.f, 0.f, 0.f};
#pragma unroll
  for (int vv = 0; vv < 4; ++vv) {
    float wv = wks[wp * 4 + vv];
    acc.x += wv * sv[vv].x; acc.y += wv * sv[vv].y;
    acc.z += wv * sv[vv].z; acc.w += wv * sv[vv].w;
  }
  if (wp == 1) part[lane] = acc;
  __syncthreads();
  if (wp == 0) {
    float4 pp = part[lane];
    acc.x += pp.x; acc.y += pp.y; acc.z += pp.z; acc.w += pp.w;
    *reinterpret_cast<float4*>(msda_w + (size_t)bq * kC + ch) = acc;
  }
}

extern "C" void kernel_launch(void* const* d_in, const int* in_sizes, int n_in,
                              void* d_out, int out_size, void* d_ws, size_t ws_size,
                              hipStream_t stream) {
  if (n_in < 13) return;
  const float* query = (const float*)d_in[0];
  const float* value = (const float*)d_in[1];
  const float* camk  = (const float*)d_in[2];
  const float* Wv    = (const float*)d_in[3];
  const float* bv    = (const float*)d_in[4];
  const float* Wo    = (const float*)d_in[5];
  const float* bo    = (const float*)d_in[6];
  const float* Wa    = (const float*)d_in[7];
  const float* ba    = (const float*)d_in[8];
  const float* Wout  = (const float*)d_in[9];
  const float* bout  = (const float*)d_in[10];
  const float* Wp    = (const float*)d_in[11];
  int bs = in_sizes[0] / (kLQ * kC);
  int MQ = bs * kLQ;          // 4224
  int MV = bs * kHF * kWF;    // 4576

  float* ws = (float*)d_ws;
  size_t o = 0;
  float* valp    = ws + o; o += (size_t)MV * kC;
  float* uv      = ws + o; o += (size_t)MQ * 16;
  float* qcat    = ws + o; o += (size_t)MQ * 128;
  float* msda_w  = ws + o; o += (size_t)MQ * kC;
  float* WoutWp  = ws + o; o += kC;
  float* Wcat    = ws + o; o += kC * 128;
  float* bcat    = ws + o; o += 128;
  (void)ws_size; (void)out_size;

  float* outp = (float*)d_out;
  float* out_grd  = outp;                          // bs*LQ*C
  float* out_mhi  = outp + (size_t)MQ * kC;        // bs*LQ
  float* out_keep = out_mhi + (size_t)MQ;          // bs*LQ

  int nGeomBlk = (MQ + 255) / 256;
  k_setup<<<nGeomBlk + 128 + kC / 4, 256, 0, stream>>>(
      camk, Wout, Wp, Wo, bo, Wa, ba, uv, out_keep, WoutWp, Wcat, bcat, bs, nGeomBlk);
  int yb0 = (MV + 31) / 32;
  int yb1 = (MQ + 31) / 32;
  gemm_dual<<<dim3(4, yb0 + yb1), 256, 0, stream>>>(
      value, Wv, bv, valp, MV, kC, kC, yb0,
      query, Wcat, bcat, qcat, MQ, 128, kC, 2);
  k_fused<<<MQ, 128, 0, stream>>>(valp, uv, qcat, WoutWp, msda_w, out_mhi);
  gemm_res<<<dim3(4, yb1), 256, 0, stream>>>(msda_w, Wout, bout, query, out_grd,
                                             MQ, kC, kC);
}